// Round 9
// baseline (7341.705 us; speedup 1.0000x reference)
//
#include <hip/hip_runtime.h>
#include <math.h>
#include <cstddef>

#define N_PTS 131072
#define SDIM  512
#define D1    513

static constexpr int NITER = 100;
static constexpr int BLK   = 512;            // 8 waves / block
static constexpr int GRID  = 512;            // 2 blocks / CU
static constexpr int WPB   = BLK / 64;       // 8 waves per block
static constexpr int NW    = GRID * WPB;     // 4096 waves
static constexpr int NPAIR = N_PTS / 2;      // 65536 row-pairs
static constexpr int PPW   = NPAIR / NW;     // 16 pairs per wave

struct Ws {
  unsigned int ticket;
  unsigned int pad[3];
  double colsum[514];          // [0..511] spatial, [512] t-sum, [513] cc-sum
  double part[514][GRID];      // column-major per-block partials
  float  mean[513];            // [0] = time coordinate
  float  pad2[3];
  float  t_tab[N_PTS];         // precomputed sqrt(1+|x_i|^2)
};

// ---------------- streaming kernel: 2 pairs (4 rows) per loop iteration ----------------
// INIT: computes sq trees, writes t_tab, accumulates w=1 sums.
// iter: loads t from t_tab, computes only dot trees (2 butterfly chains).
template<bool INIT>
__global__ __launch_bounds__(BLK, 4)
void big_kernel(const float* __restrict__ data, Ws* __restrict__ ws, int rev)
{
  const int l    = threadIdx.x & 63;
  const int sl   = l & 31;       // lane within half
  const int half = l >> 5;       // 0: even row of pair, 1: odd row
  const int wid  = threadIdx.x >> 6;
  const int gw   = blockIdx.x * WPB + wid;   // 0..NW-1

  float  m0 = 0.f;
  float4 mk0 = {0,0,0,0}, mk1 = {0,0,0,0}, mk2 = {0,0,0,0}, mk3 = {0,0,0,0};
  if constexpr (!INIT) {
    m0 = ws->mean[0];
    const float4* mp = (const float4*)(ws->mean + 1);
    mk0 = mp[0*32 + sl]; mk1 = mp[1*32 + sl];
    mk2 = mp[2*32 + sl]; mk3 = mp[3*32 + sl];
  }

  // f32 weighted accumulators; lane covers cols (j*32+sl)*4 + i
  float accf[4][4] = {};
  double acc_t = 0.0, acc_cc = 0.0;

  const int p0 = gw * PPW;

#define LDP(R, p) do {                                                        \
    int pr_ = rev ? (NPAIR - 1 - (p)) : (p);                                  \
    const float4* b_ = (const float4*)(data + (size_t)(2 * pr_ + half) * SDIM); \
    R##0 = b_[0*32 + sl]; R##1 = b_[1*32 + sl];                               \
    R##2 = b_[2*32 + sl]; R##3 = b_[3*32 + sl];                               \
  } while (0)

  float4 A0, A1, A2, A3, B0, B1, B2, B3, P0, P1, P2, P3, Q0, Q1, Q2, Q3;
  LDP(A, p0 + 0);
  LDP(B, p0 + 1);

  for (int kk = 0; kk < PPW; kk += 2) {
    const bool more = (kk + 2 < PPW);
    if (more) { LDP(P, p0 + kk + 2); LDP(Q, p0 + kk + 3); }

    const int pA = p0 + kk, pB = p0 + kk + 1;
    const int prA = rev ? (NPAIR - 1 - pA) : pA;
    const int prB = rev ? (NPAIR - 1 - pB) : pB;

    float tA, tB, wA, wB;

    if constexpr (INIT) {
      // sq trees (only needed once, to build t_tab)
      float sqA = A0.x * A0.x;
      sqA = fmaf(A0.y, A0.y, sqA); sqA = fmaf(A0.z, A0.z, sqA); sqA = fmaf(A0.w, A0.w, sqA);
      sqA = fmaf(A1.x, A1.x, sqA); sqA = fmaf(A1.y, A1.y, sqA);
      sqA = fmaf(A1.z, A1.z, sqA); sqA = fmaf(A1.w, A1.w, sqA);
      float sqA2 = A2.x * A2.x;
      sqA2 = fmaf(A2.y, A2.y, sqA2); sqA2 = fmaf(A2.z, A2.z, sqA2); sqA2 = fmaf(A2.w, A2.w, sqA2);
      sqA2 = fmaf(A3.x, A3.x, sqA2); sqA2 = fmaf(A3.y, A3.y, sqA2);
      sqA2 = fmaf(A3.z, A3.z, sqA2); sqA2 = fmaf(A3.w, A3.w, sqA2);
      sqA += sqA2;

      float sqB = B0.x * B0.x;
      sqB = fmaf(B0.y, B0.y, sqB); sqB = fmaf(B0.z, B0.z, sqB); sqB = fmaf(B0.w, B0.w, sqB);
      sqB = fmaf(B1.x, B1.x, sqB); sqB = fmaf(B1.y, B1.y, sqB);
      sqB = fmaf(B1.z, B1.z, sqB); sqB = fmaf(B1.w, B1.w, sqB);
      float sqB2 = B2.x * B2.x;
      sqB2 = fmaf(B2.y, B2.y, sqB2); sqB2 = fmaf(B2.z, B2.z, sqB2); sqB2 = fmaf(B2.w, B2.w, sqB2);
      sqB2 = fmaf(B3.x, B3.x, sqB2); sqB2 = fmaf(B3.y, B3.y, sqB2);
      sqB2 = fmaf(B3.z, B3.z, sqB2); sqB2 = fmaf(B3.w, B3.w, sqB2);
      sqB += sqB2;

      #pragma unroll
      for (int m = 1; m < 32; m <<= 1) {
        sqA += __shfl_xor(sqA, m);
        sqB += __shfl_xor(sqB, m);
      }

      tA = sqrtf(1.0f + sqA);
      tB = sqrtf(1.0f + sqB);
      wA = 1.0f; wB = 1.0f;
      if (sl == 0) {
        ws->t_tab[2 * prA + half] = tA;
        ws->t_tab[2 * prB + half] = tB;
        acc_t += (double)tA + (double)tB;
      }
    } else {
      // t from table (broadcast load, same addr across the 32-lane half)
      tA = ws->t_tab[2 * prA + half];
      tB = ws->t_tab[2 * prB + half];

      float dA = A0.x * mk0.x;
      dA = fmaf(A0.y, mk0.y, dA); dA = fmaf(A0.z, mk0.z, dA); dA = fmaf(A0.w, mk0.w, dA);
      dA = fmaf(A1.x, mk1.x, dA); dA = fmaf(A1.y, mk1.y, dA);
      dA = fmaf(A1.z, mk1.z, dA); dA = fmaf(A1.w, mk1.w, dA);
      float dA2 = A2.x * mk2.x;
      dA2 = fmaf(A2.y, mk2.y, dA2); dA2 = fmaf(A2.z, mk2.z, dA2); dA2 = fmaf(A2.w, mk2.w, dA2);
      dA2 = fmaf(A3.x, mk3.x, dA2); dA2 = fmaf(A3.y, mk3.y, dA2);
      dA2 = fmaf(A3.z, mk3.z, dA2); dA2 = fmaf(A3.w, mk3.w, dA2);
      float dotA = dA + dA2;

      float dB = B0.x * mk0.x;
      dB = fmaf(B0.y, mk0.y, dB); dB = fmaf(B0.z, mk0.z, dB); dB = fmaf(B0.w, mk0.w, dB);
      dB = fmaf(B1.x, mk1.x, dB); dB = fmaf(B1.y, mk1.y, dB);
      dB = fmaf(B1.z, mk1.z, dB); dB = fmaf(B1.w, mk1.w, dB);
      float dB2 = B2.x * mk2.x;
      dB2 = fmaf(B2.y, mk2.y, dB2); dB2 = fmaf(B2.z, mk2.z, dB2); dB2 = fmaf(B2.w, mk2.w, dB2);
      dB2 = fmaf(B3.x, mk3.x, dB2); dB2 = fmaf(B3.y, mk3.y, dB2);
      dB2 = fmaf(B3.z, mk3.z, dB2); dB2 = fmaf(B3.w, mk3.w, dB2);
      float dotB = dB + dB2;

      #pragma unroll
      for (int m = 1; m < 32; m <<= 1) {
        dotA += __shfl_xor(dotA, m);
        dotB += __shfl_xor(dotB, m);
      }

      float aA = fmaf(m0, tA, -dotA);
      float aB = fmaf(m0, tB, -dotB);
      float xA = fmaxf(aA, 1.0f + 1e-5f);
      float xB = fmaxf(aB, 1.0f + 1e-5f);
      float sA = sqrtf(fmaf(xA, xA, -1.0f));
      float sB = sqrtf(fmaf(xB, xB, -1.0f));
      float ddA = logf(xA + sA);
      float ddB = logf(xB + sB);
      wA = ddA / sA;
      wB = ddB / sB;
      if (sl == 0) {
        acc_cc += fma((double)wA, (double)xA, (double)wB * (double)xB);
        acc_t  += fma((double)wA, (double)tA, (double)wB * (double)tB);
      }
    }

    // f32 weighted accumulation, both pairs fused
    accf[0][0] = fmaf(wA, A0.x, fmaf(wB, B0.x, accf[0][0]));
    accf[0][1] = fmaf(wA, A0.y, fmaf(wB, B0.y, accf[0][1]));
    accf[0][2] = fmaf(wA, A0.z, fmaf(wB, B0.z, accf[0][2]));
    accf[0][3] = fmaf(wA, A0.w, fmaf(wB, B0.w, accf[0][3]));
    accf[1][0] = fmaf(wA, A1.x, fmaf(wB, B1.x, accf[1][0]));
    accf[1][1] = fmaf(wA, A1.y, fmaf(wB, B1.y, accf[1][1]));
    accf[1][2] = fmaf(wA, A1.z, fmaf(wB, B1.z, accf[1][2]));
    accf[1][3] = fmaf(wA, A1.w, fmaf(wB, B1.w, accf[1][3]));
    accf[2][0] = fmaf(wA, A2.x, fmaf(wB, B2.x, accf[2][0]));
    accf[2][1] = fmaf(wA, A2.y, fmaf(wB, B2.y, accf[2][1]));
    accf[2][2] = fmaf(wA, A2.z, fmaf(wB, B2.z, accf[2][2]));
    accf[2][3] = fmaf(wA, A2.w, fmaf(wB, B2.w, accf[2][3]));
    accf[3][0] = fmaf(wA, A3.x, fmaf(wB, B3.x, accf[3][0]));
    accf[3][1] = fmaf(wA, A3.y, fmaf(wB, B3.y, accf[3][1]));
    accf[3][2] = fmaf(wA, A3.z, fmaf(wB, B3.z, accf[3][2]));
    accf[3][3] = fmaf(wA, A3.w, fmaf(wB, B3.w, accf[3][3]));

    if (more) {
      A0 = P0; A1 = P1; A2 = P2; A3 = P3;
      B0 = Q0; B1 = Q1; B2 = Q2; B3 = Q3;
    }
  }
#undef LDP

  // merge the two halves (same column sets): xor-32 shuffle
  #pragma unroll
  for (int j = 0; j < 4; ++j) {
    #pragma unroll
    for (int i = 0; i < 4; ++i) accf[j][i] += __shfl_xor(accf[j][i], 32);
  }
  acc_t  += __shfl_xor(acc_t, 32);
  acc_cc += __shfl_xor(acc_cc, 32);

  __shared__ double s_red[WPB][514];
  if (half == 0) {
    #pragma unroll
    for (int j = 0; j < 4; ++j) {
      #pragma unroll
      for (int i = 0; i < 4; ++i) s_red[wid][(j*32 + sl)*4 + i] = (double)accf[j][i];
    }
  }
  if (l == 0) { s_red[wid][512] = acc_t; s_red[wid][513] = acc_cc; }
  __syncthreads();

  for (int c = threadIdx.x; c < 514; c += BLK) {
    double s = 0.0;
    #pragma unroll
    for (int w2 = 0; w2 < WPB; ++w2) s += s_red[w2][c];
    ws->part[c][blockIdx.x] = s;
  }
}

// ---------------- finalize (device): one wave does the exp-map update ----------------
template<bool INIT>
__device__ void finalize_wave(Ws* __restrict__ ws, int l)
{
  double sv[9];
  #pragma unroll
  for (int q = 0; q < 9; ++q) {
    int c = q * 64 + l;
    sv[q] = 0.0;
    if (c < D1) sv[q] = ws->colsum[(c == 0) ? 512 : (c - 1)];
  }

  if constexpr (INIT) {
    double r[9]; double s2 = 0.0;
    #pragma unroll
    for (int q = 0; q < 9; ++q) {
      int c = q * 64 + l;
      r[q] = 0.0;
      if (c < D1) { r[q] = sv[q] / (double)N_PTS; s2 += r[q] * r[q]; }
    }
    #pragma unroll
    for (int m = 1; m < 64; m <<= 1) s2 += __shfl_xor(s2, m);
    double r0 = __shfl(r[0], 0);
    double inv = 1.0 / sqrt(fabs(s2 - 2.0 * r0 * r0));
    #pragma unroll
    for (int q = 0; q < 9; ++q) {
      int c = q * 64 + l;
      if (c < D1) ws->mean[c] = (float)(r[q] * inv);
    }
  } else {
    double cc = ws->colsum[513];
    double mv[9], yv[9]; double sy = 0.0;
    #pragma unroll
    for (int q = 0; q < 9; ++q) {
      int c = q * 64 + l;
      mv[q] = 0.0; yv[q] = 0.0;
      if (c < D1) {
        double m = (double)ws->mean[c];
        double y = 0.02 * (sv[q] - cc * m) / (double)N_PTS;  // y = -R*g, R=0.01
        mv[q] = m; yv[q] = y;
        sy += y * y;
      }
    }
    #pragma unroll
    for (int m = 1; m < 64; m <<= 1) sy += __shfl_xor(sy, m);
    double y0 = __shfl(yv[0], 0);
    double n = sqrt(fabs(sy - 2.0 * y0 * y0));
    n = fmax(n, 1e-5);
    double ch = cosh(n);
    double sn = (n < 1e-4) ? (1.0 + n * n / 6.0) : (sinh(n) / n);
    double nm[9]; double s2 = 0.0;
    #pragma unroll
    for (int q = 0; q < 9; ++q) {
      int c = q * 64 + l;
      nm[q] = 0.0;
      if (c < D1) { nm[q] = ch * mv[q] + sn * yv[q]; s2 += nm[q] * nm[q]; }
    }
    #pragma unroll
    for (int m = 1; m < 64; m <<= 1) s2 += __shfl_xor(s2, m);
    double m0n = __shfl(nm[0], 0);
    double inv = 1.0 / sqrt(fabs(s2 - 2.0 * m0n * m0n));
    #pragma unroll
    for (int q = 0; q < 9; ++q) {
      int c = q * 64 + l;
      if (c < D1) ws->mean[c] = (float)(nm[q] * inv);
    }
  }
}

// ---------------- per-column reduce + fused ticketed finalize ----------------
template<bool INIT>
__global__ __launch_bounds__(64)
void colreduce_kernel(Ws* __restrict__ ws)
{
  const int c = blockIdx.x;       // 0..513
  const int l = threadIdx.x;
  const double* col = ws->part[c];
  double s = 0.0;
  #pragma unroll
  for (int k = 0; k < GRID / 64; ++k) s += col[l + 64 * k];
  #pragma unroll
  for (int m = 1; m < 64; m <<= 1) s += __shfl_xor(s, m);
  if (l == 0) ws->colsum[c] = s;

  // ticket: last block to finish runs the exp-map update
  __shared__ unsigned int s_t;
  __threadfence();                               // release colsum write
  if (l == 0) s_t = atomicAdd(&ws->ticket, 1u);
  __syncthreads();
  if (s_t == 513u) {
    __threadfence();                             // acquire all colsum writes
    finalize_wave<INIT>(ws, l);
    if (l == 0) ws->ticket = 0u;                 // reset for next iteration/replay
  }
}

__global__ void write_out_kernel(const float* __restrict__ mean, float* __restrict__ out)
{
  int i = threadIdx.x;
  if (i < SDIM) out[i] = mean[1 + i];
}

extern "C" void kernel_launch(void* const* d_in, const int* in_sizes, int n_in,
                              void* d_out, int out_size, void* d_ws, size_t ws_size,
                              hipStream_t stream)
{
  (void)in_sizes; (void)n_in; (void)out_size; (void)ws_size;
  const float* data = (const float*)d_in[0];
  Ws* ws = (Ws*)d_ws;

  // zero the ticket (everything else fully overwritten each pass)
  hipMemsetAsync(d_ws, 0, 16, stream);

  // init: t_tab + mean = normalize(mean over N of projected)
  big_kernel<true><<<dim3(GRID), dim3(BLK), 0, stream>>>(data, ws, 0);
  colreduce_kernel<true><<<dim3(514), dim3(64), 0, stream>>>(ws);

  for (int it = 0; it < NITER; ++it) {
    big_kernel<false><<<dim3(GRID), dim3(BLK), 0, stream>>>(data, ws, (it & 1) ^ 1);
    colreduce_kernel<false><<<dim3(514), dim3(64), 0, stream>>>(ws);
  }

  float* meanp = (float*)((char*)d_ws + offsetof(Ws, mean));
  write_out_kernel<<<dim3(1), dim3(512), 0, stream>>>(meanp, (float*)d_out);
}

// Round 10
// 4044.710 us; speedup vs baseline: 1.8151x; 1.8151x over previous
//
#include <hip/hip_runtime.h>
#include <hip/hip_fp16.h>
#include <math.h>
#include <cstddef>

#define N_PTS 131072
#define SDIM  512
#define D1    513

static constexpr int NITER = 100;
static constexpr int BLK   = 512;            // 8 waves / block
static constexpr int GRID  = 512;            // 2 blocks / CU
static constexpr int WPB   = BLK / 64;       // 8 waves per block
static constexpr int NW    = GRID * WPB;     // 4096 waves
static constexpr int NPAIR = N_PTS / 2;      // 65536 row-pairs
static constexpr int PPW   = NPAIR / NW;     // 16 pairs per wave

struct Ws {
  double colsum[514];          // [0..511] spatial, [512] t-sum, [513] cc-sum
  double part[514][GRID];      // column-major per-block partials
  float  mean[513];            // [0] = time coordinate
  float  padA[3];
  float  t_tab[N_PTS];         // precomputed sqrt(1+|x_i|^2) (f32, exact)
};
// fp16 data copy lives at 256B-aligned offset after Ws in d_ws.

__device__ __forceinline__ float2 cvt2(unsigned u) {
  union { unsigned u; __half2 h; } c; c.u = u; return __half22float2(c.h);
}
__device__ __forceinline__ unsigned pack2(float a, float b) {
  union { unsigned u; __half2 h; } c; c.h = __floats2half2_rn(a, b); return c.u;
}

// ================= INIT: f32 read -> t_tab + fp16 copy + w=1 partials =================
__global__ __launch_bounds__(BLK, 4)
void init_kernel(const float* __restrict__ data, __half* __restrict__ hdata,
                 Ws* __restrict__ ws)
{
  const int l    = threadIdx.x & 63;
  const int sl   = l & 31;
  const int half = l >> 5;
  const int wid  = threadIdx.x >> 6;
  const int gw   = blockIdx.x * WPB + wid;

  float accf[16] = {};
  double acc_t = 0.0;

  const int p0 = gw * PPW;

  float4 v0, v1, v2, v3, n0, n1, n2, n3;
  {
    const float4* f4 = (const float4*)(data + (size_t)(2 * p0 + half) * SDIM);
    v0 = f4[2*sl]; v1 = f4[2*sl+1]; v2 = f4[64+2*sl]; v3 = f4[64+2*sl+1];
  }

  for (int k = 0; k < PPW; ++k) {
    if (k + 1 < PPW) {
      const float4* f4 = (const float4*)(data + (size_t)(2 * (p0 + k + 1) + half) * SDIM);
      n0 = f4[2*sl]; n1 = f4[2*sl+1]; n2 = f4[64+2*sl]; n3 = f4[64+2*sl+1];
    } else { n0 = v0; n1 = v1; n2 = v2; n3 = v3; }

    const int row = 2 * (p0 + k) + half;

    // fp16 copy (layout: lane sl -> cols [8sl..8sl+8) and [256+8sl..+8))
    {
      uint4 ua, ub;
      ua.x = pack2(v0.x, v0.y); ua.y = pack2(v0.z, v0.w);
      ua.z = pack2(v1.x, v1.y); ua.w = pack2(v1.z, v1.w);
      ub.x = pack2(v2.x, v2.y); ub.y = pack2(v2.z, v2.w);
      ub.z = pack2(v3.x, v3.y); ub.w = pack2(v3.z, v3.w);
      uint4* hb = (uint4*)(hdata + (size_t)row * SDIM);
      hb[sl] = ua; hb[32 + sl] = ub;
    }

    // sq tree + butterfly -> t
    float sqa = v0.x * v0.x;
    sqa = fmaf(v0.y, v0.y, sqa); sqa = fmaf(v0.z, v0.z, sqa); sqa = fmaf(v0.w, v0.w, sqa);
    sqa = fmaf(v1.x, v1.x, sqa); sqa = fmaf(v1.y, v1.y, sqa);
    sqa = fmaf(v1.z, v1.z, sqa); sqa = fmaf(v1.w, v1.w, sqa);
    float sqb = v2.x * v2.x;
    sqb = fmaf(v2.y, v2.y, sqb); sqb = fmaf(v2.z, v2.z, sqb); sqb = fmaf(v2.w, v2.w, sqb);
    sqb = fmaf(v3.x, v3.x, sqb); sqb = fmaf(v3.y, v3.y, sqb);
    sqb = fmaf(v3.z, v3.z, sqb); sqb = fmaf(v3.w, v3.w, sqb);
    float sq = sqa + sqb;
    #pragma unroll
    for (int m = 1; m < 32; m <<= 1) sq += __shfl_xor(sq, m);

    float t = sqrtf(1.0f + sq);
    if (sl == 0) { ws->t_tab[row] = t; acc_t += (double)t; }

    // w = 1 accumulation
    accf[0]  += v0.x; accf[1]  += v0.y; accf[2]  += v0.z; accf[3]  += v0.w;
    accf[4]  += v1.x; accf[5]  += v1.y; accf[6]  += v1.z; accf[7]  += v1.w;
    accf[8]  += v2.x; accf[9]  += v2.y; accf[10] += v2.z; accf[11] += v2.w;
    accf[12] += v3.x; accf[13] += v3.y; accf[14] += v3.z; accf[15] += v3.w;

    v0 = n0; v1 = n1; v2 = n2; v3 = n3;
  }

  #pragma unroll
  for (int i = 0; i < 16; ++i) accf[i] += __shfl_xor(accf[i], 32);
  acc_t += __shfl_xor(acc_t, 32);

  __shared__ double s_red[WPB][514];
  if (half == 0) {
    #pragma unroll
    for (int i = 0; i < 8; ++i) {
      s_red[wid][8*sl + i]       = (double)accf[i];
      s_red[wid][256 + 8*sl + i] = (double)accf[8 + i];
    }
  }
  if (l == 0) { s_red[wid][512] = acc_t; s_red[wid][513] = 0.0; }
  __syncthreads();

  for (int c = threadIdx.x; c < 514; c += BLK) {
    double s = 0.0;
    #pragma unroll
    for (int w2 = 0; w2 < WPB; ++w2) s += s_red[w2][c];
    ws->part[c][blockIdx.x] = s;
  }
}

// ================= ITER: fp16 + t_tab (L3-resident), 2 pairs/iter, 3-deep prefetch ====
__global__ __launch_bounds__(BLK, 4)
void iter_kernel(const __half* __restrict__ hdata, Ws* __restrict__ ws)
{
  const int l    = threadIdx.x & 63;
  const int sl   = l & 31;
  const int half = l >> 5;
  const int wid  = threadIdx.x >> 6;
  const int gw   = blockIdx.x * WPB + wid;

  const float m0 = ws->mean[0];
  const float4* mp4 = (const float4*)(ws->mean + 1);
  const float4 mkA0 = mp4[2*sl],      mkA1 = mp4[2*sl + 1];       // cols 8sl..+8
  const float4 mkB0 = mp4[64 + 2*sl], mkB1 = mp4[64 + 2*sl + 1];  // cols 256+8sl..+8

  float accf[16] = {};
  double acc_t = 0.0, acc_cc = 0.0;

  const int p0 = gw * PPW;
  const float* __restrict__ ttab = ws->t_tab;

#define LDH(Ra, Rb, p) do {                                                   \
    const uint4* b_ = (const uint4*)(hdata + (size_t)(2 * (p) + half) * SDIM);\
    Ra = b_[sl]; Rb = b_[32 + sl];                                            \
  } while (0)

  uint4 Aa, Ab, Ba, Bb, Pa, Pb, Qa, Qb, Ra, Rb, Sa, Sb;
  LDH(Aa, Ab, p0 + 0);
  LDH(Ba, Bb, p0 + 1);
  LDH(Pa, Pb, p0 + 2);
  LDH(Qa, Qb, p0 + 3);
  Ra = Aa; Rb = Ab; Sa = Ba; Sb = Bb;

  for (int kk = 0; kk < PPW; kk += 2) {
    if (kk + 4 < PPW) {
      LDH(Ra, Rb, p0 + kk + 4);
      LDH(Sa, Sb, p0 + kk + 5);
    }
    // t loads issued early (broadcast within half)
    const float tA = ttab[2 * (p0 + kk)     + half];
    const float tB = ttab[2 * (p0 + kk + 1) + half];

    // dot trees from fp16
    float2 f;
    f = cvt2(Aa.x); float dA  = f.x * mkA0.x;        dA  = fmaf(f.y, mkA0.y, dA);
    f = cvt2(Aa.y); dA  = fmaf(f.x, mkA0.z, dA);     dA  = fmaf(f.y, mkA0.w, dA);
    f = cvt2(Aa.z); dA  = fmaf(f.x, mkA1.x, dA);     dA  = fmaf(f.y, mkA1.y, dA);
    f = cvt2(Aa.w); dA  = fmaf(f.x, mkA1.z, dA);     dA  = fmaf(f.y, mkA1.w, dA);
    f = cvt2(Ab.x); float dA2 = f.x * mkB0.x;        dA2 = fmaf(f.y, mkB0.y, dA2);
    f = cvt2(Ab.y); dA2 = fmaf(f.x, mkB0.z, dA2);    dA2 = fmaf(f.y, mkB0.w, dA2);
    f = cvt2(Ab.z); dA2 = fmaf(f.x, mkB1.x, dA2);    dA2 = fmaf(f.y, mkB1.y, dA2);
    f = cvt2(Ab.w); dA2 = fmaf(f.x, mkB1.z, dA2);    dA2 = fmaf(f.y, mkB1.w, dA2);
    float dotA = dA + dA2;

    f = cvt2(Ba.x); float dB  = f.x * mkA0.x;        dB  = fmaf(f.y, mkA0.y, dB);
    f = cvt2(Ba.y); dB  = fmaf(f.x, mkA0.z, dB);     dB  = fmaf(f.y, mkA0.w, dB);
    f = cvt2(Ba.z); dB  = fmaf(f.x, mkA1.x, dB);     dB  = fmaf(f.y, mkA1.y, dB);
    f = cvt2(Ba.w); dB  = fmaf(f.x, mkA1.z, dB);     dB  = fmaf(f.y, mkA1.w, dB);
    f = cvt2(Bb.x); float dB2 = f.x * mkB0.x;        dB2 = fmaf(f.y, mkB0.y, dB2);
    f = cvt2(Bb.y); dB2 = fmaf(f.x, mkB0.z, dB2);    dB2 = fmaf(f.y, mkB0.w, dB2);
    f = cvt2(Bb.z); dB2 = fmaf(f.x, mkB1.x, dB2);    dB2 = fmaf(f.y, mkB1.y, dB2);
    f = cvt2(Bb.w); dB2 = fmaf(f.x, mkB1.z, dB2);    dB2 = fmaf(f.y, mkB1.w, dB2);
    float dotB = dB + dB2;

    #pragma unroll
    for (int m = 1; m < 32; m <<= 1) {
      dotA += __shfl_xor(dotA, m);
      dotB += __shfl_xor(dotB, m);
    }

    const float aA = fmaf(m0, tA, -dotA);
    const float aB = fmaf(m0, tB, -dotB);
    const float xA = fmaxf(aA, 1.0f + 1e-5f);
    const float xB = fmaxf(aB, 1.0f + 1e-5f);
    const float sA = sqrtf(fmaf(xA, xA, -1.0f));
    const float sB = sqrtf(fmaf(xB, xB, -1.0f));
    const float ddA = logf(xA + sA);
    const float ddB = logf(xB + sB);
    const float wA = ddA / sA;
    const float wB = ddB / sB;
    if (sl == 0) {
      acc_cc += fma((double)wA, (double)xA, (double)wB * (double)xB);
      acc_t  += fma((double)wA, (double)tA, (double)wB * (double)tB);
    }

    // weighted accumulation (re-convert; uint4s still live)
    float2 a0, a1;
    a0 = cvt2(Aa.x); a1 = cvt2(Ba.x);
    accf[0]  = fmaf(wA, a0.x, fmaf(wB, a1.x, accf[0]));
    accf[1]  = fmaf(wA, a0.y, fmaf(wB, a1.y, accf[1]));
    a0 = cvt2(Aa.y); a1 = cvt2(Ba.y);
    accf[2]  = fmaf(wA, a0.x, fmaf(wB, a1.x, accf[2]));
    accf[3]  = fmaf(wA, a0.y, fmaf(wB, a1.y, accf[3]));
    a0 = cvt2(Aa.z); a1 = cvt2(Ba.z);
    accf[4]  = fmaf(wA, a0.x, fmaf(wB, a1.x, accf[4]));
    accf[5]  = fmaf(wA, a0.y, fmaf(wB, a1.y, accf[5]));
    a0 = cvt2(Aa.w); a1 = cvt2(Ba.w);
    accf[6]  = fmaf(wA, a0.x, fmaf(wB, a1.x, accf[6]));
    accf[7]  = fmaf(wA, a0.y, fmaf(wB, a1.y, accf[7]));
    a0 = cvt2(Ab.x); a1 = cvt2(Bb.x);
    accf[8]  = fmaf(wA, a0.x, fmaf(wB, a1.x, accf[8]));
    accf[9]  = fmaf(wA, a0.y, fmaf(wB, a1.y, accf[9]));
    a0 = cvt2(Ab.y); a1 = cvt2(Bb.y);
    accf[10] = fmaf(wA, a0.x, fmaf(wB, a1.x, accf[10]));
    accf[11] = fmaf(wA, a0.y, fmaf(wB, a1.y, accf[11]));
    a0 = cvt2(Ab.z); a1 = cvt2(Bb.z);
    accf[12] = fmaf(wA, a0.x, fmaf(wB, a1.x, accf[12]));
    accf[13] = fmaf(wA, a0.y, fmaf(wB, a1.y, accf[13]));
    a0 = cvt2(Ab.w); a1 = cvt2(Bb.w);
    accf[14] = fmaf(wA, a0.x, fmaf(wB, a1.x, accf[14]));
    accf[15] = fmaf(wA, a0.y, fmaf(wB, a1.y, accf[15]));

    Aa = Pa; Ab = Pb; Ba = Qa; Bb = Qb;
    Pa = Ra; Pb = Rb; Qa = Sa; Qb = Sb;
  }
#undef LDH

  #pragma unroll
  for (int i = 0; i < 16; ++i) accf[i] += __shfl_xor(accf[i], 32);
  acc_t  += __shfl_xor(acc_t, 32);
  acc_cc += __shfl_xor(acc_cc, 32);

  __shared__ double s_red[WPB][514];
  if (half == 0) {
    #pragma unroll
    for (int i = 0; i < 8; ++i) {
      s_red[wid][8*sl + i]       = (double)accf[i];
      s_red[wid][256 + 8*sl + i] = (double)accf[8 + i];
    }
  }
  if (l == 0) { s_red[wid][512] = acc_t; s_red[wid][513] = acc_cc; }
  __syncthreads();

  for (int c = threadIdx.x; c < 514; c += BLK) {
    double s = 0.0;
    #pragma unroll
    for (int w2 = 0; w2 < WPB; ++w2) s += s_red[w2][c];
    ws->part[c][blockIdx.x] = s;
  }
}

// ================= FALLBACK (R8, proven): f32 streaming, 2 pairs/iter ================
template<bool INIT>
__global__ __launch_bounds__(BLK, 4)
void big_kernel(const float* __restrict__ data, Ws* __restrict__ ws, int rev)
{
  const int l    = threadIdx.x & 63;
  const int sl   = l & 31;
  const int half = l >> 5;
  const int wid  = threadIdx.x >> 6;
  const int gw   = blockIdx.x * WPB + wid;

  float  m0 = 0.f;
  float4 mk0 = {0,0,0,0}, mk1 = {0,0,0,0}, mk2 = {0,0,0,0}, mk3 = {0,0,0,0};
  if constexpr (!INIT) {
    m0 = ws->mean[0];
    const float4* mp = (const float4*)(ws->mean + 1);
    mk0 = mp[0*32 + sl]; mk1 = mp[1*32 + sl];
    mk2 = mp[2*32 + sl]; mk3 = mp[3*32 + sl];
  }

  float accf[4][4] = {};
  double acc_t = 0.0, acc_cc = 0.0;
  const int p0 = gw * PPW;

#define LDP(R, p) do {                                                        \
    int pr_ = rev ? (NPAIR - 1 - (p)) : (p);                                  \
    const float4* b_ = (const float4*)(data + (size_t)(2 * pr_ + half) * SDIM); \
    R##0 = b_[0*32 + sl]; R##1 = b_[1*32 + sl];                               \
    R##2 = b_[2*32 + sl]; R##3 = b_[3*32 + sl];                               \
  } while (0)

  float4 A0, A1, A2, A3, B0, B1, B2, B3, P0, P1, P2, P3, Q0, Q1, Q2, Q3;
  LDP(A, p0 + 0);
  LDP(B, p0 + 1);

  for (int kk = 0; kk < PPW; kk += 2) {
    const bool more = (kk + 2 < PPW);
    if (more) { LDP(P, p0 + kk + 2); LDP(Q, p0 + kk + 3); }

    float sqA = A0.x * A0.x;
    sqA = fmaf(A0.y, A0.y, sqA); sqA = fmaf(A0.z, A0.z, sqA); sqA = fmaf(A0.w, A0.w, sqA);
    sqA = fmaf(A1.x, A1.x, sqA); sqA = fmaf(A1.y, A1.y, sqA);
    sqA = fmaf(A1.z, A1.z, sqA); sqA = fmaf(A1.w, A1.w, sqA);
    float sqA2 = A2.x * A2.x;
    sqA2 = fmaf(A2.y, A2.y, sqA2); sqA2 = fmaf(A2.z, A2.z, sqA2); sqA2 = fmaf(A2.w, A2.w, sqA2);
    sqA2 = fmaf(A3.x, A3.x, sqA2); sqA2 = fmaf(A3.y, A3.y, sqA2);
    sqA2 = fmaf(A3.z, A3.z, sqA2); sqA2 = fmaf(A3.w, A3.w, sqA2);
    sqA += sqA2;

    float sqB = B0.x * B0.x;
    sqB = fmaf(B0.y, B0.y, sqB); sqB = fmaf(B0.z, B0.z, sqB); sqB = fmaf(B0.w, B0.w, sqB);
    sqB = fmaf(B1.x, B1.x, sqB); sqB = fmaf(B1.y, B1.y, sqB);
    sqB = fmaf(B1.z, B1.z, sqB); sqB = fmaf(B1.w, B1.w, sqB);
    float sqB2 = B2.x * B2.x;
    sqB2 = fmaf(B2.y, B2.y, sqB2); sqB2 = fmaf(B2.z, B2.z, sqB2); sqB2 = fmaf(B2.w, B2.w, sqB2);
    sqB2 = fmaf(B3.x, B3.x, sqB2); sqB2 = fmaf(B3.y, B3.y, sqB2);
    sqB2 = fmaf(B3.z, B3.z, sqB2); sqB2 = fmaf(B3.w, B3.w, sqB2);
    sqB += sqB2;

    float dotA = 0.f, dotB = 0.f;
    if constexpr (!INIT) {
      float dA = A0.x * mk0.x;
      dA = fmaf(A0.y, mk0.y, dA); dA = fmaf(A0.z, mk0.z, dA); dA = fmaf(A0.w, mk0.w, dA);
      dA = fmaf(A1.x, mk1.x, dA); dA = fmaf(A1.y, mk1.y, dA);
      dA = fmaf(A1.z, mk1.z, dA); dA = fmaf(A1.w, mk1.w, dA);
      float dA2 = A2.x * mk2.x;
      dA2 = fmaf(A2.y, mk2.y, dA2); dA2 = fmaf(A2.z, mk2.z, dA2); dA2 = fmaf(A2.w, mk2.w, dA2);
      dA2 = fmaf(A3.x, mk3.x, dA2); dA2 = fmaf(A3.y, mk3.y, dA2);
      dA2 = fmaf(A3.z, mk3.z, dA2); dA2 = fmaf(A3.w, mk3.w, dA2);
      dotA = dA + dA2;

      float dB = B0.x * mk0.x;
      dB = fmaf(B0.y, mk0.y, dB); dB = fmaf(B0.z, mk0.z, dB); dB = fmaf(B0.w, mk0.w, dB);
      dB = fmaf(B1.x, mk1.x, dB); dB = fmaf(B1.y, mk1.y, dB);
      dB = fmaf(B1.z, mk1.z, dB); dB = fmaf(B1.w, mk1.w, dB);
      float dB2 = B2.x * mk2.x;
      dB2 = fmaf(B2.y, mk2.y, dB2); dB2 = fmaf(B2.z, mk2.z, dB2); dB2 = fmaf(B2.w, mk2.w, dB2);
      dB2 = fmaf(B3.x, mk3.x, dB2); dB2 = fmaf(B3.y, mk3.y, dB2);
      dB2 = fmaf(B3.z, mk3.z, dB2); dB2 = fmaf(B3.w, mk3.w, dB2);
      dotB = dB + dB2;
    }

    #pragma unroll
    for (int m = 1; m < 32; m <<= 1) {
      sqA += __shfl_xor(sqA, m);
      sqB += __shfl_xor(sqB, m);
      if constexpr (!INIT) {
        dotA += __shfl_xor(dotA, m);
        dotB += __shfl_xor(dotB, m);
      }
    }

    float tA = sqrtf(1.0f + sqA);
    float tB = sqrtf(1.0f + sqB);
    float wA, wB;
    if constexpr (INIT) {
      wA = 1.0f; wB = 1.0f;
      if (sl == 0) acc_t += (double)tA + (double)tB;
    } else {
      float aA = fmaf(m0, tA, -dotA);
      float aB = fmaf(m0, tB, -dotB);
      float xA = fmaxf(aA, 1.0f + 1e-5f);
      float xB = fmaxf(aB, 1.0f + 1e-5f);
      float sA = sqrtf(fmaf(xA, xA, -1.0f));
      float sB = sqrtf(fmaf(xB, xB, -1.0f));
      float dA = logf(xA + sA);
      float dB = logf(xB + sB);
      wA = dA / sA;
      wB = dB / sB;
      if (sl == 0) {
        acc_cc += fma((double)wA, (double)xA, (double)wB * (double)xB);
        acc_t  += fma((double)wA, (double)tA, (double)wB * (double)tB);
      }
    }

    accf[0][0] = fmaf(wA, A0.x, fmaf(wB, B0.x, accf[0][0]));
    accf[0][1] = fmaf(wA, A0.y, fmaf(wB, B0.y, accf[0][1]));
    accf[0][2] = fmaf(wA, A0.z, fmaf(wB, B0.z, accf[0][2]));
    accf[0][3] = fmaf(wA, A0.w, fmaf(wB, B0.w, accf[0][3]));
    accf[1][0] = fmaf(wA, A1.x, fmaf(wB, B1.x, accf[1][0]));
    accf[1][1] = fmaf(wA, A1.y, fmaf(wB, B1.y, accf[1][1]));
    accf[1][2] = fmaf(wA, A1.z, fmaf(wB, B1.z, accf[1][2]));
    accf[1][3] = fmaf(wA, A1.w, fmaf(wB, B1.w, accf[1][3]));
    accf[2][0] = fmaf(wA, A2.x, fmaf(wB, B2.x, accf[2][0]));
    accf[2][1] = fmaf(wA, A2.y, fmaf(wB, B2.y, accf[2][1]));
    accf[2][2] = fmaf(wA, A2.z, fmaf(wB, B2.z, accf[2][2]));
    accf[2][3] = fmaf(wA, A2.w, fmaf(wB, B2.w, accf[2][3]));
    accf[3][0] = fmaf(wA, A3.x, fmaf(wB, B3.x, accf[3][0]));
    accf[3][1] = fmaf(wA, A3.y, fmaf(wB, B3.y, accf[3][1]));
    accf[3][2] = fmaf(wA, A3.z, fmaf(wB, B3.z, accf[3][2]));
    accf[3][3] = fmaf(wA, A3.w, fmaf(wB, B3.w, accf[3][3]));

    if (more) {
      A0 = P0; A1 = P1; A2 = P2; A3 = P3;
      B0 = Q0; B1 = Q1; B2 = Q2; B3 = Q3;
    }
  }
#undef LDP

  #pragma unroll
  for (int j = 0; j < 4; ++j) {
    #pragma unroll
    for (int i = 0; i < 4; ++i) accf[j][i] += __shfl_xor(accf[j][i], 32);
  }
  acc_t  += __shfl_xor(acc_t, 32);
  acc_cc += __shfl_xor(acc_cc, 32);

  __shared__ double s_red[WPB][514];
  if (half == 0) {
    #pragma unroll
    for (int j = 0; j < 4; ++j) {
      #pragma unroll
      for (int i = 0; i < 4; ++i) s_red[wid][(j*32 + sl)*4 + i] = (double)accf[j][i];
    }
  }
  if (l == 0) { s_red[wid][512] = acc_t; s_red[wid][513] = acc_cc; }
  __syncthreads();

  for (int c = threadIdx.x; c < 514; c += BLK) {
    double s = 0.0;
    #pragma unroll
    for (int w2 = 0; w2 < WPB; ++w2) s += s_red[w2][c];
    ws->part[c][blockIdx.x] = s;
  }
}

// ---------------- per-column reduce: one wave per column ----------------
__global__ __launch_bounds__(64)
void colreduce_kernel(Ws* __restrict__ ws)
{
  const int c = blockIdx.x;
  const int l = threadIdx.x;
  const double* col = ws->part[c];
  double s = 0.0;
  #pragma unroll
  for (int k = 0; k < GRID / 64; ++k) s += col[l + 64 * k];
  #pragma unroll
  for (int m = 1; m < 64; m <<= 1) s += __shfl_xor(s, m);
  if (l == 0) ws->colsum[c] = s;
}

// ---------------- finalize: one wave does the exp-map update ----------------
template<bool INIT>
__global__ __launch_bounds__(64)
void finalize_kernel(Ws* __restrict__ ws)
{
  const int l = threadIdx.x;
  double sv[9];
  #pragma unroll
  for (int q = 0; q < 9; ++q) {
    int c = q * 64 + l;
    sv[q] = 0.0;
    if (c < D1) sv[q] = ws->colsum[(c == 0) ? 512 : (c - 1)];
  }

  if constexpr (INIT) {
    double r[9]; double s2 = 0.0;
    #pragma unroll
    for (int q = 0; q < 9; ++q) {
      int c = q * 64 + l;
      r[q] = 0.0;
      if (c < D1) { r[q] = sv[q] / (double)N_PTS; s2 += r[q] * r[q]; }
    }
    #pragma unroll
    for (int m = 1; m < 64; m <<= 1) s2 += __shfl_xor(s2, m);
    double r0 = __shfl(r[0], 0);
    double inv = 1.0 / sqrt(fabs(s2 - 2.0 * r0 * r0));
    #pragma unroll
    for (int q = 0; q < 9; ++q) {
      int c = q * 64 + l;
      if (c < D1) ws->mean[c] = (float)(r[q] * inv);
    }
  } else {
    double cc = ws->colsum[513];
    double mv[9], yv[9]; double sy = 0.0;
    #pragma unroll
    for (int q = 0; q < 9; ++q) {
      int c = q * 64 + l;
      mv[q] = 0.0; yv[q] = 0.0;
      if (c < D1) {
        double m = (double)ws->mean[c];
        double y = 0.02 * (sv[q] - cc * m) / (double)N_PTS;  // y = -R*g, R=0.01
        mv[q] = m; yv[q] = y;
        sy += y * y;
      }
    }
    #pragma unroll
    for (int m = 1; m < 64; m <<= 1) sy += __shfl_xor(sy, m);
    double y0 = __shfl(yv[0], 0);
    double n = sqrt(fabs(sy - 2.0 * y0 * y0));
    n = fmax(n, 1e-5);
    double ch = cosh(n);
    double sn = (n < 1e-4) ? (1.0 + n * n / 6.0) : (sinh(n) / n);
    double nm[9]; double s2 = 0.0;
    #pragma unroll
    for (int q = 0; q < 9; ++q) {
      int c = q * 64 + l;
      nm[q] = 0.0;
      if (c < D1) { nm[q] = ch * mv[q] + sn * yv[q]; s2 += nm[q] * nm[q]; }
    }
    #pragma unroll
    for (int m = 1; m < 64; m <<= 1) s2 += __shfl_xor(s2, m);
    double m0n = __shfl(nm[0], 0);
    double inv = 1.0 / sqrt(fabs(s2 - 2.0 * m0n * m0n));
    #pragma unroll
    for (int q = 0; q < 9; ++q) {
      int c = q * 64 + l;
      if (c < D1) ws->mean[c] = (float)(nm[q] * inv);
    }
  }
}

__global__ void write_out_kernel(const float* __restrict__ mean, float* __restrict__ out)
{
  int i = threadIdx.x;
  if (i < SDIM) out[i] = mean[1 + i];
}

extern "C" void kernel_launch(void* const* d_in, const int* in_sizes, int n_in,
                              void* d_out, int out_size, void* d_ws, size_t ws_size,
                              hipStream_t stream)
{
  (void)in_sizes; (void)n_in; (void)out_size;
  const float* data = (const float*)d_in[0];
  Ws* ws = (Ws*)d_ws;

  const size_t hoff = (sizeof(Ws) + 255) & ~(size_t)255;
  const size_t need = hoff + (size_t)N_PTS * SDIM * sizeof(__half) + 256;

  if (ws_size >= need) {
    // fp16 L3-resident path
    __half* hdata = (__half*)((char*)d_ws + hoff);

    init_kernel<<<dim3(GRID), dim3(BLK), 0, stream>>>(data, hdata, ws);
    colreduce_kernel<<<dim3(514), dim3(64), 0, stream>>>(ws);
    finalize_kernel<true><<<dim3(1), dim3(64), 0, stream>>>(ws);

    for (int it = 0; it < NITER; ++it) {
      iter_kernel<<<dim3(GRID), dim3(BLK), 0, stream>>>(hdata, ws);
      colreduce_kernel<<<dim3(514), dim3(64), 0, stream>>>(ws);
      finalize_kernel<false><<<dim3(1), dim3(64), 0, stream>>>(ws);
    }
  } else {
    // fallback: proven R8 f32 path
    big_kernel<true><<<dim3(GRID), dim3(BLK), 0, stream>>>(data, ws, 0);
    colreduce_kernel<<<dim3(514), dim3(64), 0, stream>>>(ws);
    finalize_kernel<true><<<dim3(1), dim3(64), 0, stream>>>(ws);

    for (int it = 0; it < NITER; ++it) {
      big_kernel<false><<<dim3(GRID), dim3(BLK), 0, stream>>>(data, ws, (it & 1) ^ 1);
      colreduce_kernel<<<dim3(514), dim3(64), 0, stream>>>(ws);
      finalize_kernel<false><<<dim3(1), dim3(64), 0, stream>>>(ws);
    }
  }

  float* meanp = (float*)((char*)d_ws + offsetof(Ws, mean));
  write_out_kernel<<<dim3(1), dim3(512), 0, stream>>>(meanp, (float*)d_out);
}